// Round 1
// baseline (2546.515 us; speedup 1.0000x reference)
//
#include <hip/hip_runtime.h>

typedef float f32x2 __attribute__((ext_vector_type(2)));

#define BATCH 256
#define D 128
#define T 2048
#define G3 384  // 3*D

// Fast, safe sigmoid/tanh via hardware v_exp_f32
__device__ __forceinline__ float fast_sigmoid(float s) {
    return 1.0f / (1.0f + __expf(-s));   // s->-inf: exp->inf -> 0; s->+inf: -> 1
}
__device__ __forceinline__ float fast_tanh(float s) {
    return 1.0f - 2.0f / (1.0f + __expf(2.0f * s)); // s->+inf: 1; s->-inf: -1
}

// grid: 256 blocks (one per batch row); block: 768 threads
// tid = kh*384 + c : kh splits K=128 into two halves, c is the gate column.
__global__ __launch_bounds__(768) void gru_fused(
    const float* __restrict__ x,   // [B, D, T]
    const float* __restrict__ W,   // [D, 3D]
    const float* __restrict__ U,   // [D, 3D]
    const float* __restrict__ b,   // [3D]
    float* __restrict__ out)       // [B, D, T]
{
    const int bb  = blockIdx.x;
    const int tid = threadIdx.x;
    const int kh  = (tid >= G3) ? 1 : 0;
    const int c   = tid - kh * G3;
    const int kbase = kh * 64;

    // Weight columns in registers (fully static indexing -> no scratch)
    f32x2 wcol[32], ucol[32];
    #pragma unroll
    for (int k2 = 0; k2 < 32; ++k2) {
        wcol[k2][0] = W[(size_t)(kbase + 2*k2 + 0) * G3 + c];
        wcol[k2][1] = W[(size_t)(kbase + 2*k2 + 1) * G3 + c];
        ucol[k2][0] = U[(size_t)(kbase + 2*k2 + 0) * G3 + c];
        ucol[k2][1] = U[(size_t)(kbase + 2*k2 + 1) * G3 + c];
    }
    const float bias = b[c];

    __shared__ float xs[2][D];     // double-buffered x_t
    __shared__ float hs[D];        // hidden state
    __shared__ float px[G3], ph[G3]; // k-partials (kh=1 -> kh=0), reused as n-stash
    __shared__ float rs[D], ns[D];

    if (tid < D) {
        hs[tid]   = 0.0f;
        xs[0][tid] = x[((size_t)bb * D + tid) * T];  // stage t=0
    }
    __syncthreads();

    const float* __restrict__ xrow = x   + (size_t)bb * D * T;
    float* __restrict__       orow = out + (size_t)bb * D * T;

    float zv = 0.0f;  // persistent z for tid < D (the h-update threads)

    for (int t = 0; t < T; ++t) {
        const float* xcur = xs[t & 1] + kbase;
        const float* hcur = hs + kbase;

        f32x2 axv = {0.0f, 0.0f}, ahv = {0.0f, 0.0f};
        #pragma unroll
        for (int k2 = 0; k2 < 32; ++k2) {
            f32x2 xv = *(const f32x2*)(xcur + 2*k2);
            f32x2 hv = *(const f32x2*)(hcur + 2*k2);
            axv += xv * wcol[k2];
            ahv += hv * ucol[k2];
        }
        float ax = axv[0] + axv[1];
        float ah = ahv[0] + ahv[1];
        if (kh) { px[c] = ax; ph[c] = ah; }

        // Prefetch next x_t (threads 128..255; strided reads, L1/L2-absorbed)
        if (t + 1 < T && tid >= 128 && tid < 256) {
            const int k = tid - 128;
            xs[(t + 1) & 1][k] = xrow[(size_t)k * T + (t + 1)];
        }
        __syncthreads();   // B1: k-partials + next-x visible

        if (!kh) {
            ax += px[c];
            ah += ph[c];
            if (c < D) {                       // z gate
                zv = fast_sigmoid(ax + ah + bias);
            } else if (c < 2*D) {              // r gate
                rs[c - D] = fast_sigmoid(ax + ah + bias);
            } else {                           // n gate: stash, needs r
                px[c] = ax + bias;             // xn
                ph[c] = ah;                    // hn
            }
        }
        __syncthreads();   // B2: rs ready

        if (!kh && c >= 2*D) {
            float r = rs[c - 2*D];
            ns[c - 2*D] = fast_tanh(px[c] + r * ph[c]);
        }
        __syncthreads();   // B3: ns ready

        if (tid < D) {
            float n    = ns[tid];
            float hnew = zv * hs[tid] + (1.0f - zv) * n;
            hs[tid] = hnew;
            orow[(size_t)tid * T + t] = hnew;   // strided; L2 write-combines
        }
        __syncthreads();   // B4: hs updated for next step
    }
}

extern "C" void kernel_launch(void* const* d_in, const int* in_sizes, int n_in,
                              void* d_out, int out_size, void* d_ws, size_t ws_size,
                              hipStream_t stream) {
    const float* x = (const float*)d_in[0];
    const float* W = (const float*)d_in[1];
    const float* U = (const float*)d_in[2];
    const float* b = (const float*)d_in[3];
    float* out     = (float*)d_out;
    hipLaunchKernelGGL(gru_fused, dim3(BATCH), dim3(768), 0, stream,
                       x, W, U, b, out);
}